// Round 3
// baseline (84.867 us; speedup 1.0000x reference)
//
#include <hip/hip_runtime.h>

#define T_LEN 1024
#define B_ROWS 32768
#define CHUNK 16
#define NCHUNK (T_LEN / CHUNK)

typedef float v2f __attribute__((ext_vector_type(2)));

// One thread per batch row. 512 waves total (hard parallelism cap), spread as
// block=64/grid=512 so all 256 CUs get 2 single-wave blocks (2 busy SIMDs/CU).
// With 1 wave/SIMD the step cost is per-wave ISSUE cycles; pack full-rate ops
// into v_pk_* pairs and keep transcendental count minimal (5 exp2 + 2 rcp).
__global__ __launch_bounds__(64, 1) void lstm_scan_kernel(
    const float* __restrict__ x,
    const float* __restrict__ params,
    float* __restrict__ out) {

    const int row = blockIdx.x * 64 + threadIdx.x;

    // 12 scalar params (uniform address -> s_load, one-time cost).
    const float w_fg0 = params[0], w_fg1 = params[1],  b_fg0 = params[2];
    const float w_ig0 = params[3], w_ig1 = params[4],  b_ig0 = params[5];
    const float w_in0 = params[6], w_in1 = params[7],  b_in0 = params[8];
    const float w_og0 = params[9], w_og1 = params[10], b_og0 = params[11];

    const float L = 1.44269504088896340736f;  // log2(e)
    // sigmoid(z) = 1/(1+exp2(-L z)); tanh(z) = (1-exp2(-2L z))/(1+exp2(-2L z)).
    // Fold -L (resp. -2L for the tanh input gate) into the coefficients.
    // Pair layout: {fg, ig} and {in, og}.
    const v2f a01  = { -L * w_fg0,       -L * w_ig0 };
    const v2f c101 = { -L * w_fg1,       -L * w_ig1 };
    const v2f c001 = { -L * b_fg0,       -L * b_ig0 };
    const v2f a23  = { -2.f * L * w_in0, -L * w_og0 };
    const v2f c123 = { -2.f * L * w_in1, -L * w_og1 };
    const v2f c023 = { -2.f * L * b_in0, -L * b_og0 };
    const float n2L = -2.f * L;

    const float4* xr = reinterpret_cast<const float4*>(x + (size_t)row * T_LEN);

    float lm = 0.f, sm = 0.f;

    // Register double-buffer: one 64B line (16 floats = 16 timesteps) ahead.
    float4 c0 = xr[0], c1 = xr[1], c2 = xr[2], c3 = xr[3];

    for (int c = 0; c < NCHUNK; ++c) {
        const int cn = (c + 1 < NCHUNK) ? (c + 1) : c;
        const float4* nx = xr + 4 * cn;
        float4 n0 = nx[0], n1 = nx[1], n2 = nx[2], n3 = nx[3];

        float xs[CHUNK];
        xs[0]  = c0.x; xs[1]  = c0.y; xs[2]  = c0.z; xs[3]  = c0.w;
        xs[4]  = c1.x; xs[5]  = c1.y; xs[6]  = c1.z; xs[7]  = c1.w;
        xs[8]  = c2.x; xs[9]  = c2.y; xs[10] = c2.z; xs[11] = c2.w;
        xs[12] = c3.x; xs[13] = c3.y; xs[14] = c3.z; xs[15] = c3.w;

        #pragma unroll
        for (int j = 0; j < CHUNK; ++j) {
            const float xv = xs[j];
            const v2f xx = { xv, xv };
            const v2f ss = { sm, sm };

            // Gate arguments, packed: pre_g = x*c1+c0 (off-chain), then +sm*a.
            const v2f pre01 = __builtin_elementwise_fma(xx, c101, c001);
            const v2f pre23 = __builtin_elementwise_fma(xx, c123, c023);
            const v2f g01   = __builtin_elementwise_fma(ss, a01, pre01);
            const v2f g23   = __builtin_elementwise_fma(ss, a23, pre23);

            // E_g = exp(-z_g) (exp(-2 z) for the tanh gate). Transcendentals
            // are scalar-only; 4 of the 5 per step.
            const float Ef = __builtin_amdgcn_exp2f(g01.x);
            const float Ei = __builtin_amdgcn_exp2f(g01.y);
            const float Ep = __builtin_amdgcn_exp2f(g23.x);
            const float Eo = __builtin_amdgcn_exp2f(g23.y);

            const v2f E01 = { Ef, Ei };
            const v2f E23 = { Ep, Eo };
            const v2f A01 = E01 + 1.f;   // {Af, Ai}
            const v2f A23 = E23 + 1.f;   // {Ap, Ao}
            const float Bp = 1.f - Ep;

            // lm_new = lm/(1+Ef) + (1-Ep)/((1+Ep)(1+Ei))
            //        = (lm*Ap*Ai + Bp*Af) / (Af*Ap*Ai)     -- one rcp
            const float t1  = A23.x * A01.y;                // Ap*Ai
            const float t2  = Bp * A01.x;                   // Bp*Af
            const float num = __builtin_fmaf(lm, t1, t2);
            const float den = t1 * A01.x;
            const float rd  = __builtin_amdgcn_rcpf(den);
            lm = num * rd;

            // sm_new = tanh(lm)*og = (1-EL)/((1+EL)(1+Eo)), EL = exp2(-2L*lm)
            // signed. Clamp arg to <=60 so all downstream values stay normal
            // f32 (no inf*0, no denormal-flush): lm->-inf gives sm -> -og.
            const float ar = fminf(60.f, (n2L * num) * rd);
            const float EL = __builtin_amdgcn_exp2f(ar);
            const float AL = EL + 1.f;
            const float BL = 1.f - EL;
            const float R  = __builtin_amdgcn_rcpf(AL * A23.y);  // 1/((1+EL)*Ao)
            sm = BL * R;
        }

        c0 = n0; c1 = n1; c2 = n2; c3 = n3;
    }

    out[row] = sm;
}

extern "C" void kernel_launch(void* const* d_in, const int* in_sizes, int n_in,
                              void* d_out, int out_size, void* d_ws, size_t ws_size,
                              hipStream_t stream) {
    const float* x      = (const float*)d_in[0];
    const float* params = (const float*)d_in[1];
    float* out          = (float*)d_out;

    dim3 grid(B_ROWS / 64);
    dim3 block(64);
    hipLaunchKernelGGL(lstm_scan_kernel, grid, block, 0, stream, x, params, out);
}

// Round 5
// 77.507 us; speedup vs baseline: 1.0950x; 1.0950x over previous
//
#include <hip/hip_runtime.h>

#define T_LEN 1024
#define B_ROWS 32768
#define CHUNK 16
#define NCHUNK (T_LEN / CHUNK)

typedef float v2f __attribute__((ext_vector_type(2)));

// One LSTM timestep. Reads xv, updates lm/sm (locals in scope).
// 5 exp2 + 2 rcp (quarter-rate) + ~20 full-rate ops, chain-optimal factoring:
//   lm_new = (lm*Ap*Ai + (1-Ep)*Af) / (Af*Ap*Ai)            -- one rcp
//   sm_new = (1-EL) / ((1+EL)*(1+Eo)), EL=exp2(-2L*lm_new)  -- one rcp
// Clamp exp2 arg at 60 so lm -> -inf degrades to sm -> -og (no inf*0 NaN).
#define STEP(xv) do {                                                         \
    const v2f xx = { (xv), (xv) };                                            \
    const v2f ss = { sm, sm };                                                \
    const v2f g01 = __builtin_elementwise_fma(ss, a01,                        \
                      __builtin_elementwise_fma(xx, c101, c001));             \
    const v2f g23 = __builtin_elementwise_fma(ss, a23,                        \
                      __builtin_elementwise_fma(xx, c123, c023));             \
    const float Ef = __builtin_amdgcn_exp2f(g01.x);                           \
    const float Ei = __builtin_amdgcn_exp2f(g01.y);                           \
    const float Ep = __builtin_amdgcn_exp2f(g23.x);                           \
    const float Eo = __builtin_amdgcn_exp2f(g23.y);                           \
    const v2f A01 = (v2f){Ef, Ei} + 1.f;  /* {Af, Ai} */                      \
    const v2f A23 = (v2f){Ep, Eo} + 1.f;  /* {Ap, Ao} */                      \
    const float Bp  = 1.f - Ep;                                               \
    const float t1  = A23.x * A01.y;                                          \
    const float t2  = Bp * A01.x;                                             \
    const float num = __builtin_fmaf(lm, t1, t2);                             \
    const float den = t1 * A01.x;                                             \
    const float rd  = __builtin_amdgcn_rcpf(den);                             \
    lm = num * rd;                                                            \
    const float ar = fminf(60.f, (n2L * num) * rd);                           \
    const float EL = __builtin_amdgcn_exp2f(ar);                              \
    const float AL = EL + 1.f;                                                \
    const float BL = 1.f - EL;                                                \
    sm = BL * __builtin_amdgcn_rcpf(AL * A23.y);                              \
} while (0)

// Pin 4 float4s (16 floats) into VGPRs: forces the pending loads' waitcnt to
// land HERE and makes the values opaque (no per-use reload rematerialization).
#define PIN4(a, b, cc, d)                                                     \
    asm volatile("" : "+v"(a.x), "+v"(a.y), "+v"(a.z), "+v"(a.w),             \
                      "+v"(b.x), "+v"(b.y), "+v"(b.z), "+v"(b.w),             \
                      "+v"(cc.x), "+v"(cc.y), "+v"(cc.z), "+v"(cc.w),         \
                      "+v"(d.x), "+v"(d.y), "+v"(d.z), "+v"(d.w))

// One thread per batch row; 512 single-wave blocks -> 2 busy SIMDs per CU
// (512 waves is the hard parallelism cap of this op).
__global__ __launch_bounds__(64, 1) void lstm_scan_kernel(
    const float* __restrict__ x,
    const float* __restrict__ params,
    float* __restrict__ out) {

    const int row = blockIdx.x * 64 + threadIdx.x;

    const float w_fg0 = params[0], w_fg1 = params[1],  b_fg0 = params[2];
    const float w_ig0 = params[3], w_ig1 = params[4],  b_ig0 = params[5];
    const float w_in0 = params[6], w_in1 = params[7],  b_in0 = params[8];
    const float w_og0 = params[9], w_og1 = params[10], b_og0 = params[11];

    const float L = 1.44269504088896340736f;  // log2(e)
    // sigmoid(z)=1/(1+exp2(-L z)); tanh(z)=(1-exp2(-2L z))/(1+exp2(-2L z)).
    // Pair layout: {fg, ig} and {in(tanh, -2L), og}.
    const v2f a01  = { -L * w_fg0,       -L * w_ig0 };
    const v2f c101 = { -L * w_fg1,       -L * w_ig1 };
    const v2f c001 = { -L * b_fg0,       -L * b_ig0 };
    const v2f a23  = { -2.f * L * w_in0, -L * w_og0 };
    const v2f c123 = { -2.f * L * w_in1, -L * w_og1 };
    const v2f c023 = { -2.f * L * b_in0, -L * b_og0 };
    const float n2L = -2.f * L;

    const float4* xr = reinterpret_cast<const float4*>(x + (size_t)row * T_LEN);

    float lm = 0.f, sm = 0.f;

    // Prologue: load chunk 0 and pin it into registers.
    float4 c0 = xr[0], c1 = xr[1], c2 = xr[2], c3 = xr[3];
    PIN4(c0, c1, c2, c3);

    for (int c = 0; c < NCHUNK; ++c) {
        // Issue next-chunk loads (clamped on last iter), BEFORE the steps.
        const int cn = (c + 1 < NCHUNK) ? (c + 1) : c;
        const float4* nx = xr + 4 * cn;
        float4 n0 = nx[0], n1 = nx[1], n2 = nx[2], n3 = nx[3];
        // Keep the load issue above the compute (no sinking past this point).
        __builtin_amdgcn_sched_barrier(0);

        STEP(c0.x); STEP(c0.y); STEP(c0.z); STEP(c0.w);
        STEP(c1.x); STEP(c1.y); STEP(c1.z); STEP(c1.w);
        STEP(c2.x); STEP(c2.y); STEP(c2.z); STEP(c2.w);
        STEP(c3.x); STEP(c3.y); STEP(c3.z); STEP(c3.w);

        // Wait for the prefetched chunk here (after compute), then rotate.
        PIN4(n0, n1, n2, n3);
        c0 = n0; c1 = n1; c2 = n2; c3 = n3;
    }

    out[row] = sm;
}

extern "C" void kernel_launch(void* const* d_in, const int* in_sizes, int n_in,
                              void* d_out, int out_size, void* d_ws, size_t ws_size,
                              hipStream_t stream) {
    const float* x      = (const float*)d_in[0];
    const float* params = (const float*)d_in[1];
    float* out          = (float*)d_out;

    dim3 grid(B_ROWS / 64);
    dim3 block(64);
    hipLaunchKernelGGL(lstm_scan_kernel, grid, block, 0, stream, x, params, out);
}

// Round 6
// 71.004 us; speedup vs baseline: 1.1952x; 1.0916x over previous
//
#include <hip/hip_runtime.h>

#define T_LEN 1024
#define B_ROWS 32768
#define CHUNK 16
#define NCHUNK (T_LEN / CHUNK)

typedef float v2f __attribute__((ext_vector_type(2)));

// One LSTM timestep. State: lm, and (BL, R) with sm == BL*R (never formed).
//   gates:  g_g = h_g*R + pre_g,  h_g = a_g*BL   (a_g*sm == h_g*R)
//   lm'   = (lm*Ap*Ai + (1-Ep)*Af) / (Af*Ap*Ai)          -- one rcp
//   EL    = exp2(clamp(-2L*num)*rd);  BL' = 1-EL;  R' = rcp((1+EL)*(1+Eo))
// Clamp is on num (before *rd): den>=1 => rd<=1 => ar<=60, no exp2 overflow,
// and the fmin runs in parallel with rcp(den) instead of after it.
#define STEP(xv) do {                                                         \
    const v2f xx  = { (xv), (xv) };                                           \
    const v2f BLv = { BL, BL };                                               \
    const v2f Rv  = { R, R };                                                 \
    const v2f pre01 = __builtin_elementwise_fma(xx, c101, c001);              \
    const v2f pre23 = __builtin_elementwise_fma(xx, c123, c023);              \
    const v2f h01 = BLv * a01;                                                \
    const v2f h23 = BLv * a23;                                                \
    const v2f g01 = __builtin_elementwise_fma(h01, Rv, pre01);                \
    const v2f g23 = __builtin_elementwise_fma(h23, Rv, pre23);                \
    const float Ef = __builtin_amdgcn_exp2f(g01.x);                           \
    const float Ei = __builtin_amdgcn_exp2f(g01.y);                           \
    const float Ep = __builtin_amdgcn_exp2f(g23.x);                           \
    const float Eo = __builtin_amdgcn_exp2f(g23.y);                           \
    const v2f A01 = (v2f){Ef, Ei} + 1.f;  /* {Af, Ai} */                      \
    const v2f A23 = (v2f){Ep, Eo} + 1.f;  /* {Ap, Ao} */                      \
    const float Bp  = 1.f - Ep;                                               \
    const float t1  = A23.x * A01.y;                                          \
    const float t2  = Bp * A01.x;                                             \
    const float num = __builtin_fmaf(lm, t1, t2);                             \
    const float den = t1 * A01.x;                                             \
    const float rd  = __builtin_amdgcn_rcpf(den);                             \
    const float tt  = fminf(60.f, n2L * num);   /* parallel with rcp(den) */  \
    lm = num * rd;                                                            \
    const float ar = tt * rd;                                                 \
    const float EL = __builtin_amdgcn_exp2f(ar);                              \
    const float AL = EL + 1.f;                                                \
    BL = 1.f - EL;                                                            \
    R  = __builtin_amdgcn_rcpf(AL * A23.y);                                   \
} while (0)

// Pin 4 float4s (16 floats) into VGPRs: forces the pending loads' waitcnt to
// land HERE and makes the values opaque (no per-use reload rematerialization).
#define PIN4(a, b, cc, d)                                                     \
    asm volatile("" : "+v"(a.x), "+v"(a.y), "+v"(a.z), "+v"(a.w),             \
                      "+v"(b.x), "+v"(b.y), "+v"(b.z), "+v"(b.w),             \
                      "+v"(cc.x), "+v"(cc.y), "+v"(cc.z), "+v"(cc.w),         \
                      "+v"(d.x), "+v"(d.y), "+v"(d.z), "+v"(d.w))

// One thread per batch row; 512 single-wave blocks -> 2 busy SIMDs per CU
// (512 waves is the hard parallelism cap of this op). Wave-packing is a
// provable wash (total issue / SIMDs-fed is invariant), so the levers are
// per-step chain length and issue count only.
__global__ __launch_bounds__(64, 1) void lstm_scan_kernel(
    const float* __restrict__ x,
    const float* __restrict__ params,
    float* __restrict__ out) {

    const int row = blockIdx.x * 64 + threadIdx.x;

    const float w_fg0 = params[0], w_fg1 = params[1],  b_fg0 = params[2];
    const float w_ig0 = params[3], w_ig1 = params[4],  b_ig0 = params[5];
    const float w_in0 = params[6], w_in1 = params[7],  b_in0 = params[8];
    const float w_og0 = params[9], w_og1 = params[10], b_og0 = params[11];

    const float L = 1.44269504088896340736f;  // log2(e)
    // sigmoid(z)=1/(1+exp2(-L z)); tanh(z)=(1-exp2(-2L z))/(1+exp2(-2L z)).
    // Pair layout: {fg, ig} and {in(tanh, -2L), og}.
    const v2f a01  = { -L * w_fg0,       -L * w_ig0 };
    const v2f c101 = { -L * w_fg1,       -L * w_ig1 };
    const v2f c001 = { -L * b_fg0,       -L * b_ig0 };
    const v2f a23  = { -2.f * L * w_in0, -L * w_og0 };
    const v2f c123 = { -2.f * L * w_in1, -L * w_og1 };
    const v2f c023 = { -2.f * L * b_in0, -L * b_og0 };
    const float n2L = -2.f * L;

    const float4* xr = reinterpret_cast<const float4*>(x + (size_t)row * T_LEN);

    float lm = 0.f;
    float BL = 0.f, R = 1.f;   // sm == BL*R == 0 initially

    // Prologue: load chunk 0 and pin it into registers.
    float4 c0 = xr[0], c1 = xr[1], c2 = xr[2], c3 = xr[3];
    PIN4(c0, c1, c2, c3);

    for (int c = 0; c < NCHUNK; ++c) {
        // Issue next-chunk loads (clamped on last iter), BEFORE the steps.
        const int cn = (c + 1 < NCHUNK) ? (c + 1) : c;
        const float4* nx = xr + 4 * cn;
        float4 n0 = nx[0], n1 = nx[1], n2 = nx[2], n3 = nx[3];
        // Keep the load issue above the compute (no sinking past this point).
        __builtin_amdgcn_sched_barrier(0);

        STEP(c0.x); STEP(c0.y); STEP(c0.z); STEP(c0.w);
        STEP(c1.x); STEP(c1.y); STEP(c1.z); STEP(c1.w);
        STEP(c2.x); STEP(c2.y); STEP(c2.z); STEP(c2.w);
        STEP(c3.x); STEP(c3.y); STEP(c3.z); STEP(c3.w);

        // Wait for the prefetched chunk here (after compute), then rotate.
        PIN4(n0, n1, n2, n3);
        c0 = n0; c1 = n1; c2 = n2; c3 = n3;
    }

    out[row] = BL * R;   // sm formed once, at the end
}

extern "C" void kernel_launch(void* const* d_in, const int* in_sizes, int n_in,
                              void* d_out, int out_size, void* d_ws, size_t ws_size,
                              hipStream_t stream) {
    const float* x      = (const float*)d_in[0];
    const float* params = (const float*)d_in[1];
    float* out          = (float*)d_out;

    dim3 grid(B_ROWS / 64);
    dim3 block(64);
    hipLaunchKernelGGL(lstm_scan_kernel, grid, block, 0, stream, x, params, out);
}